// Round 3
// baseline (864.940 us; speedup 1.0000x reference)
//
#include <hip/hip_runtime.h>
#include <math.h>

#define BATCH 16
#define NS 2048
#define NT 96
#define DIM 32
#define ROWL 2144   // NS+NT
#define EPSV 1e-30f

struct Seg { int off[3]; float sc[3]; };

// ---------------------------------------------------------------------------
// Pass 0: per-row feature transforms.
// Spatial row i: [ s (32) | n1=tanh(3*W_ss1@s) | n2=tanh(3*W_ss2@s) | q_st | k_ts ]  (160 floats)
// Temporal row j: [ t (32) | q_ts | k_st ]                                            (96 floats)
// ---------------------------------------------------------------------------
__global__ __launch_bounds__(256) void feat_kernel(
    const float* __restrict__ sp, const float* __restrict__ tp,
    const float* __restrict__ Wss1, const float* __restrict__ Wss2,
    const float* __restrict__ Wqst, const float* __restrict__ bqst,
    const float* __restrict__ Wkst, const float* __restrict__ bkst,
    const float* __restrict__ Wqts, const float* __restrict__ bqts,
    const float* __restrict__ Wkts, const float* __restrict__ bkts,
    float* __restrict__ FS, float* __restrict__ FT)
{
  __shared__ float Wl[6*1056];   // 6 matrices, padded [32][33] to kill bank conflicts
  __shared__ float bl[128];      // bqst, bkst, bqts, bkts
  __shared__ float xl[8][32];
  const int tid = threadIdx.x;
  {
    const float* Ws[6] = {Wss1, Wss2, Wqst, Wkst, Wqts, Wkts};
    #pragma unroll
    for (int m = 0; m < 6; m++){          // m is compile-time after unroll -> no scratch
      const float* W = Ws[m];
      #pragma unroll
      for (int c = 0; c < 4; c++){
        int idx = c*256 + tid;
        Wl[m*1056 + (idx>>5)*33 + (idx&31)] = W[idx];
      }
    }
    if (tid < 32)        bl[tid]       = bqst[tid];
    else if (tid < 64)   bl[tid]       = bkst[tid-32];
    else if (tid < 96)   bl[tid]       = bqts[tid-64];
    else if (tid < 128)  bl[tid]       = bkts[tid-96];
  }
  const int rs = tid >> 5;       // row-in-block 0..7
  const int f  = tid & 31;       // output feature
  const int row = blockIdx.x*8 + rs;
  const int NROWS = BATCH*NS;
  const int TOT   = NROWS + BATCH*NT;
  const bool valid = row < TOT;
  const bool isS   = row < NROWS;
  if (valid){
    const float* xp = isS ? (sp + (size_t)row*DIM) : (tp + (size_t)(row-NROWS)*DIM);
    xl[rs][f] = xp[f];
  }
  __syncthreads();
  if (!valid) return;

  if (isS){
    float a1=0.f, a2=0.f, aq=0.f, ak=0.f;
    #pragma unroll
    for (int d=0; d<32; d++){
      float xv = xl[rs][d];
      a1 = fmaf(xv, Wl[0*1056 + f*33 + d], a1);
      a2 = fmaf(xv, Wl[1*1056 + f*33 + d], a2);
      aq = fmaf(xv, Wl[2*1056 + f*33 + d], aq);
      ak = fmaf(xv, Wl[5*1056 + f*33 + d], ak);
    }
    float* o = FS + (size_t)row*160;
    o[f]     = xl[rs][f];
    o[32+f]  = tanhf(3.0f*a1);
    o[64+f]  = tanhf(3.0f*a2);
    o[96+f]  = aq + bl[0  + f];   // bq_st
    o[128+f] = ak + bl[96 + f];   // bk_ts
  } else {
    const int rt = row - NROWS;
    float aq=0.f, ak=0.f;
    #pragma unroll
    for (int d=0; d<32; d++){
      float xv = xl[rs][d];
      aq = fmaf(xv, Wl[4*1056 + f*33 + d], aq);
      ak = fmaf(xv, Wl[3*1056 + f*33 + d], ak);
    }
    float* o = FT + (size_t)rt*96;
    o[f]     = xl[rs][f];
    o[32+f]  = aq + bl[64 + f];   // bq_ts
    o[64+f]  = ak + bl[32 + f];   // bk_st
  }
}

// ---------------------------------------------------------------------------
// Pass 1: 64x64-tile fp32 GEMM (K = 96/64/32) writing raw adjacency into out,
// plus per-region relu-max via int-bits atomicMax (relu values >= 0; signed
// int compare == float compare there, and the 0xAA ws poison is a negative
// int so any update wins -> no init kernel needed).
// ---------------------------------------------------------------------------
template<int K>
__global__ __launch_bounds__(256) void adj_tile(
    const float* __restrict__ Fu, int fustride, int NI, Seg su,
    const float* __restrict__ Fv, int fvstride, int NJ, Seg sv,
    float* __restrict__ out, int i0g, int j0g, float* __restrict__ maxslot)
{
  constexpr int KP  = K + 4;   // pad -> 2-way (free) bank aliasing only
  constexpr int F4R = K / 4;
  __shared__ __align__(16) float Ut[64*KP];
  __shared__ __align__(16) float Vt[64*KP];
  __shared__ float red[4];
  const int tid = threadIdx.x;
  const int b   = blockIdx.z;
  const int i0t = blockIdx.y*64;
  const int j0t = blockIdx.x*64;

  for (int q = tid; q < 64*F4R; q += 256){
    int row = q / F4R;
    int kk  = (q - row*F4R)*4;
    int seg = kk >> 5;
    float4 v = make_float4(0.f,0.f,0.f,0.f);
    int gi = i0t + row;
    if (gi < NI){
      const float* src = Fu + (size_t)(b*NI + gi)*fustride + su.off[seg] + (kk & 31);
      v = *(const float4*)src;
    }
    float sc = su.sc[seg];
    v.x*=sc; v.y*=sc; v.z*=sc; v.w*=sc;
    *(float4*)&Ut[row*KP + kk] = v;
  }
  for (int q = tid; q < 64*F4R; q += 256){
    int row = q / F4R;
    int kk  = (q - row*F4R)*4;
    int seg = kk >> 5;
    float4 v = make_float4(0.f,0.f,0.f,0.f);
    int gj = j0t + row;
    if (gj < NJ){
      const float* src = Fv + (size_t)(b*NJ + gj)*fvstride + sv.off[seg] + (kk & 31);
      v = *(const float4*)src;
    }
    float sc = sv.sc[seg];
    v.x*=sc; v.y*=sc; v.z*=sc; v.w*=sc;
    *(float4*)&Vt[row*KP + kk] = v;
  }
  __syncthreads();

  const int tx = tid & 15;   // j rows {tx, tx+16, tx+32, tx+48}
  const int ty = tid >> 4;   // i rows {ty, ty+16, ty+32, ty+48}
  float acc[4][4] = {};
  for (int k=0; k<K; k+=4){
    float4 a[4], bb[4];
    #pragma unroll
    for (int m=0;m<4;m++) a[m]  = *(const float4*)&Ut[(ty + 16*m)*KP + k];
    #pragma unroll
    for (int n=0;n<4;n++) bb[n] = *(const float4*)&Vt[(tx + 16*n)*KP + k];
    #pragma unroll
    for (int m=0;m<4;m++){
      #pragma unroll
      for (int n=0;n<4;n++){
        acc[m][n] = fmaf(a[m].x, bb[n].x, acc[m][n]);
        acc[m][n] = fmaf(a[m].y, bb[n].y, acc[m][n]);
        acc[m][n] = fmaf(a[m].z, bb[n].z, acc[m][n]);
        acc[m][n] = fmaf(a[m].w, bb[n].w, acc[m][n]);
      }
    }
  }

  float lmax = 0.f;
  const size_t obase = (size_t)b*ROWL*ROWL;
  #pragma unroll
  for (int m=0;m<4;m++){
    int gi = i0t + ty + 16*m;
    if (gi < NI){
      #pragma unroll
      for (int n=0;n<4;n++){
        int gj = j0t + tx + 16*n;
        if (gj < NJ){
          out[obase + (size_t)(i0g+gi)*ROWL + (j0g+gj)] = acc[m][n];
          lmax = fmaxf(lmax, acc[m][n]);
        }
      }
    }
  }
  // wave shuffle-reduce (64 lanes), then one LDS step across the 4 waves
  #pragma unroll
  for (int off = 32; off > 0; off >>= 1)
    lmax = fmaxf(lmax, __shfl_xor(lmax, off));
  if ((tid & 63) == 0) red[tid >> 6] = lmax;
  __syncthreads();
  if (tid == 0){
    float m4 = fmaxf(fmaxf(red[0], red[1]), fmaxf(red[2], red[3]));
    atomicMax((int*)maxslot, __float_as_int(m4));
  }
}

// ---------------------------------------------------------------------------
// Pass 2: out = tanh(relu(out)/(blockmax+eps)); zero strict-lower-tri of tt.
// One block per output row (B*ROWL blocks): no per-element div/mod, and the
// NS boundary lands exactly at float4-column 512 -> wave-uniform region pick.
// tanh arg is in [0,1] -> (e^{2x}-1)/(e^{2x}+1) exact-range-safe, ~5x cheaper
// than ocml tanhf.
// ---------------------------------------------------------------------------
__device__ __forceinline__ float tanh01(float x){
  float e = __expf(2.0f*x);
  return __fdividef(e - 1.0f, e + 1.0f);
}
__device__ __forceinline__ float4 uni4(float4 v, float r){
  v.x = tanh01(fmaxf(v.x,0.f)*r);
  v.y = tanh01(fmaxf(v.y,0.f)*r);
  v.z = tanh01(fmaxf(v.z,0.f)*r);
  v.w = tanh01(fmaxf(v.w,0.f)*r);
  return v;
}

__global__ __launch_bounds__(256) void uni_kernel(float* __restrict__ out,
                                                  const float* __restrict__ mx)
{
  const int row = blockIdx.x;          // b*ROWL + i
  const int i   = row % ROWL;          // one scalar magic-mod per block
  const bool top = (i < NS);
  const float rl = 1.0f/((top ? mx[0] : mx[2]) + EPSV);   // j <  NS
  const float rr = 1.0f/((top ? mx[1] : mx[3]) + EPSV);   // j >= NS
  float4* rowp = (float4*)(out + (size_t)row*ROWL);
  const int tid = threadIdx.x;

  // columns 0..511 (j in [0,2048)): left region
  rowp[tid]       = uni4(rowp[tid],       rl);
  rowp[tid + 256] = uni4(rowp[tid + 256], rl);

  // columns 512..535 (j in [2048,2144)): right region (+ tt triu mask)
  if (tid < 24){
    float4 v = uni4(rowp[tid + 512], rr);
    if (!top){
      int il = i - NS;
      int jl = 4*tid;
      if (jl+0 < il) v.x = 0.f;
      if (jl+1 < il) v.y = 0.f;
      if (jl+2 < il) v.z = 0.f;
      if (jl+3 < il) v.w = 0.f;
    }
    rowp[tid + 512] = v;
  }
}

extern "C" void kernel_launch(void* const* d_in, const int* in_sizes, int n_in,
                              void* d_out, int out_size, void* d_ws, size_t ws_size,
                              hipStream_t stream)
{
  const float* sp   = (const float*)d_in[0];
  const float* tp   = (const float*)d_in[1];
  const float* Wss1 = (const float*)d_in[2];
  const float* Wss2 = (const float*)d_in[3];
  const float* Wqst = (const float*)d_in[4];
  const float* bqst = (const float*)d_in[5];
  const float* Wkst = (const float*)d_in[6];
  const float* bkst = (const float*)d_in[7];
  const float* Wqts = (const float*)d_in[8];
  const float* bqts = (const float*)d_in[9];
  const float* Wkts = (const float*)d_in[10];
  const float* bkts = (const float*)d_in[11];
  float* out  = (float*)d_out;
  float* wsf  = (float*)d_ws;
  float* maxs = wsf;                         // 4 relu-max slots (int-bits atomicMax)
  float* FS   = wsf + 64;                    // 16*2048*160 floats (~21 MB)
  float* FT   = FS + (size_t)BATCH*NS*160;   // 16*96*96 floats   (~0.6 MB)

  feat_kernel<<<dim3((BATCH*(NS+NT))/8), 256, 0, stream>>>(
      sp,tp,Wss1,Wss2,Wqst,bqst,Wkst,bkst,Wqts,bqts,Wkts,bkts,FS,FT);

  // ss: u=[s, 3*n1, -3*n2], v=[s, n2, n1]  (K=96)
  Seg su_ss = {{0,32,64},{1.f,3.f,-3.f}};
  Seg sv_ss = {{0,64,32},{1.f,1.f,1.f}};
  adj_tile<96><<<dim3(32,32,BATCH), 256, 0, stream>>>(
      FS,160,NS,su_ss, FS,160,NS,sv_ss, out, 0,0, maxs+0);

  // st: u=[s, q_st], v=[t, k_st]  (K=64)
  Seg su_st = {{0,96,0},{1.f,1.f,0.f}};
  Seg sv_st = {{0,64,0},{1.f,1.f,0.f}};
  adj_tile<64><<<dim3(2,32,BATCH), 256, 0, stream>>>(
      FS,160,NS,su_st, FT,96,NT,sv_st, out, 0,NS, maxs+1);

  // ts: u=[t, q_ts], v=[s, k_ts]  (K=64)
  Seg su_ts = {{0,32,0},{1.f,1.f,0.f}};
  Seg sv_ts = {{0,128,0},{1.f,1.f,0.f}};
  adj_tile<64><<<dim3(32,2,BATCH), 256, 0, stream>>>(
      FT,96,NT,su_ts, FS,160,NS,sv_ts, out, NS,0, maxs+2);

  // tt: u=v=[t]  (K=32)
  Seg s_tt = {{0,0,0},{1.f,0.f,0.f}};
  adj_tile<32><<<dim3(2,2,BATCH), 256, 0, stream>>>(
      FT,96,NT,s_tt, FT,96,NT,s_tt, out, NS,NS, maxs+3);

  uni_kernel<<<BATCH*ROWL, 256, 0, stream>>>(out, maxs);
}